// Round 5
// baseline (733.709 us; speedup 1.0000x reference)
//
#include <hip/hip_runtime.h>

#define CL5_NATOMS 8192
#define CL5_NSHIFT 14
#define CL5_NROWS (CL5_NSHIFT * CL5_NATOMS)     // 114688 (k, i) rows
#define CL5_GROUP 16                            // rows per wave
#define CL5_NGROUPS (CL5_NROWS / CL5_GROUP)     // 7168
#define CL5_GPS (CL5_NGROUPS / CL5_NSHIFT)      // 512 groups per shift
// f32(27.040000000000003): JAX / NumPy>=2 weak promotion does the compare in f32.
#define CL5_C2 ((float)(5.2 * 5.2))

__device__ const int cl5_shifts[CL5_NSHIFT][3] = {
    {0, 0, 0},
    {-1, 0, 0}, {-1, -1, 0}, {0, -1, 0}, {1, -1, 0},
    {-1, 1, -1}, {0, 1, -1}, {1, 1, -1}, {-1, 0, -1},
    {0, 0, -1}, {1, 0, -1}, {-1, -1, -1}, {0, -1, -1}, {1, -1, -1}};

// Module-owned scratch (d_ws unused). Fully rewritten every call.
__device__ float cl5_px[CL5_NATOMS];
__device__ float cl5_py[CL5_NATOMS];
__device__ float cl5_pz[CL5_NATOMS];
__device__ unsigned int cl5_goff[CL5_NGROUPS];

__device__ __forceinline__ void cl5_diag(const float* __restrict__ cell, float& dgx,
                                         float& dgy, float& dgz) {
  dgx = (float)sqrt((double)cell[0] * cell[0] + (double)cell[3] * cell[3] +
                    (double)cell[6] * cell[6]);
  dgy = (float)sqrt((double)cell[1] * cell[1] + (double)cell[4] * cell[4] +
                    (double)cell[7] * cell[7]);
  dgz = (float)sqrt((double)cell[2] * cell[2] + (double)cell[5] * cell[5] +
                    (double)cell[8] * cell[8]);
}

// frac = coords @ inv(cell); frac -= floor(frac); w = frac @ cell  (f32 per-op
// rounding; exact off-diagonal zeros make FMA-vs-not immaterial here).
__global__ __launch_bounds__(256) void cl5_wrap(const float* __restrict__ coords,
                                                const float* __restrict__ cell) {
  int i = blockIdx.x * blockDim.x + threadIdx.x;
  if (i >= CL5_NATOMS) return;
  double a00 = cell[0], a01 = cell[1], a02 = cell[2];
  double a10 = cell[3], a11 = cell[4], a12 = cell[5];
  double a20 = cell[6], a21 = cell[7], a22 = cell[8];
  double det = a00 * (a11 * a22 - a12 * a21) - a01 * (a10 * a22 - a12 * a20) +
               a02 * (a10 * a21 - a11 * a20);
  double id = 1.0 / det;
  float inv[3][3];
  inv[0][0] = (float)((a11 * a22 - a12 * a21) * id);
  inv[0][1] = (float)(-(a01 * a22 - a02 * a21) * id);
  inv[0][2] = (float)((a01 * a12 - a02 * a11) * id);
  inv[1][0] = (float)(-(a10 * a22 - a12 * a20) * id);
  inv[1][1] = (float)((a00 * a22 - a02 * a20) * id);
  inv[1][2] = (float)(-(a00 * a12 - a02 * a10) * id);
  inv[2][0] = (float)((a10 * a21 - a11 * a20) * id);
  inv[2][1] = (float)(-(a00 * a21 - a01 * a20) * id);
  inv[2][2] = (float)((a00 * a11 - a01 * a10) * id);

  float x = coords[3 * i], y = coords[3 * i + 1], z = coords[3 * i + 2];
  float fr[3];
#pragma unroll
  for (int c = 0; c < 3; ++c) {
    float f = __fadd_rn(__fadd_rn(__fmul_rn(x, inv[0][c]), __fmul_rn(y, inv[1][c])),
                        __fmul_rn(z, inv[2][c]));
    fr[c] = __fsub_rn(f, floorf(f));
  }
#pragma unroll
  for (int c = 0; c < 3; ++c) {
    float w = __fadd_rn(
        __fadd_rn(__fmul_rn(fr[0], cell[0 * 3 + c]), __fmul_rn(fr[1], cell[1 * 3 + c])),
        __fmul_rn(fr[2], cell[2 * 3 + c]));
    if (c == 0) cl5_px[i] = w;
    if (c == 1) cl5_py[i] = w;
    if (c == 2) cl5_pz[i] = w;
  }
}

// d2<=c2 forces shifted atom i into a cutoff-wide boundary slab (0.09 safety
// margin over f32 rounding slack). Pruned rows provably contribute zero pairs.
__device__ __forceinline__ bool cl5_alive(float xi, float yi, float zi, int sx, int sy,
                                          int sz, float dgx, float dgy, float dgz) {
  bool a = true;
  if (sx < 0) a = a && (xi >= dgx - 5.3f); else if (sx > 0) a = a && (xi <= 5.3f);
  if (sy < 0) a = a && (yi >= dgy - 5.3f); else if (sy > 0) a = a && (yi <= 5.3f);
  if (sz < 0) a = a && (zi >= dgz - 5.3f); else if (sz > 0) a = a && (zi <= 5.3f);
  return a;
}

// One wave per 16-row group: count pairs.
__global__ __launch_bounds__(512) void cl5_count(const float* __restrict__ cell) {
  int wg = blockIdx.x * 8 + (threadIdx.x >> 6);
  int lane = threadIdx.x & 63;
  int g = (wg % CL5_NSHIFT) * CL5_GPS + (wg / CL5_NSHIFT);  // load-balance bijection
  int k = g >> 9;
  int i0 = (g & 511) * CL5_GROUP;

  float dgx, dgy, dgz;
  cl5_diag(cell, dgx, dgy, dgz);
  int sx = cl5_shifts[k][0], sy = cl5_shifts[k][1], sz = cl5_shifts[k][2];
  float sxf = __fmul_rn((float)sx, dgx);
  float syf = __fmul_rn((float)sy, dgy);
  float szf = __fmul_rn((float)sz, dgz);

  unsigned int cnt = 0;
  for (int r = 0; r < CL5_GROUP; ++r) {
    int i = i0 + r;
    float xi = cl5_px[i], yi = cl5_py[i], zi = cl5_pz[i];
    if (k != 0 && !cl5_alive(xi, yi, zi, sx, sy, sz, dgx, dgy, dgz)) continue;
    int jstart = (k == 0) ? (i & ~63) : 0;  // earlier chunks all fail i<j
    for (int j0 = jstart; j0 < CL5_NATOMS; j0 += 64) {
      int j = j0 + lane;
      float dx = __fadd_rn(__fsub_rn(xi, cl5_px[j]), sxf);
      float dy = __fadd_rn(__fsub_rn(yi, cl5_py[j]), syf);
      float dz = __fadd_rn(__fsub_rn(zi, cl5_pz[j]), szf);
      float d2 = __fadd_rn(__fadd_rn(__fmul_rn(dx, dx), __fmul_rn(dy, dy)),
                           __fmul_rn(dz, dz));
      bool ok = (d2 <= CL5_C2) && (k != 0 || i < j);
      cnt += (unsigned)__popcll(__ballot(ok));
    }
  }
  if (lane == 0) cl5_goff[g] = cnt;
}

// In-place exclusive prefix sum over 7168 group counts (7 x 1024 tiles).
__global__ __launch_bounds__(1024) void cl5_scan() {
  __shared__ unsigned int sd[1024];
  __shared__ unsigned int carry;
  int t = threadIdx.x;
  if (t == 0) carry = 0;
  __syncthreads();
  for (int base = 0; base < CL5_NGROUPS; base += 1024) {
    unsigned int v = cl5_goff[base + t];
    sd[t] = v;
    __syncthreads();
    unsigned int acc = v;
    for (int off = 1; off < 1024; off <<= 1) {
      unsigned int a = (t >= off) ? sd[t - off] : 0u;
      __syncthreads();
      acc += a;
      sd[t] = acc;
      __syncthreads();
    }
    cl5_goff[base + t] = carry + (acc - v);
    __syncthreads();
    if (t == 1023) carry += acc;
    __syncthreads();
  }
}

// Defensive: fully initialize d_out (int32) each call.
__global__ __launch_bounds__(256) void cl5_fill(int* __restrict__ out, int n) {
  for (int p = blockIdx.x * 256 + threadIdx.x; p < n; p += gridDim.x * 256) out[p] = 0;
}

// Recompute predicates (identical to count), ballot-compact, write INT32 stream:
// [ i x P | j x P | (sx,sy,sz) x P ].
__global__ __launch_bounds__(512) void cl5_emit(const float* __restrict__ cell,
                                                int* __restrict__ out, int P) {
  int wg = blockIdx.x * 8 + (threadIdx.x >> 6);
  int lane = threadIdx.x & 63;
  int g = (wg % CL5_NSHIFT) * CL5_GPS + (wg / CL5_NSHIFT);
  int k = g >> 9;
  int i0 = (g & 511) * CL5_GROUP;

  float dgx, dgy, dgz;
  cl5_diag(cell, dgx, dgy, dgz);
  int sx = cl5_shifts[k][0], sy = cl5_shifts[k][1], sz = cl5_shifts[k][2];
  float sxf = __fmul_rn((float)sx, dgx);
  float syf = __fmul_rn((float)sy, dgy);
  float szf = __fmul_rn((float)sz, dgz);

  unsigned int base = cl5_goff[g];
  for (int r = 0; r < CL5_GROUP; ++r) {
    int i = i0 + r;
    float xi = cl5_px[i], yi = cl5_py[i], zi = cl5_pz[i];
    if (k != 0 && !cl5_alive(xi, yi, zi, sx, sy, sz, dgx, dgy, dgz)) continue;
    int jstart = (k == 0) ? (i & ~63) : 0;
    for (int j0 = jstart; j0 < CL5_NATOMS; j0 += 64) {
      int j = j0 + lane;
      float dx = __fadd_rn(__fsub_rn(xi, cl5_px[j]), sxf);
      float dy = __fadd_rn(__fsub_rn(yi, cl5_py[j]), syf);
      float dz = __fadd_rn(__fsub_rn(zi, cl5_pz[j]), szf);
      float d2 = __fadd_rn(__fadd_rn(__fmul_rn(dx, dx), __fmul_rn(dy, dy)),
                           __fmul_rn(dz, dz));
      bool ok = (d2 <= CL5_C2) && (k != 0 || i < j);
      unsigned long long m = __ballot(ok);
      if (ok) {
        unsigned int pos = base + (unsigned)__popcll(m & ((1ull << lane) - 1ull));
        if (pos < (unsigned)P) {
          out[pos] = i;                              // atom_pairs row 0
          out[P + pos] = j;                          // atom_pairs row 1
          unsigned int sp = 2u * (unsigned)P + 3u * pos;  // shift_indices (P,3)
          out[sp] = sx;
          out[sp + 1] = sy;
          out[sp + 2] = sz;
        }
      }
      base += (unsigned)__popcll(m);
    }
  }
}

extern "C" void kernel_launch(void* const* d_in, const int* in_sizes, int n_in,
                              void* d_out, int out_size, void* d_ws, size_t ws_size,
                              hipStream_t stream) {
  const float* coords = (const float*)d_in[1];  // (1, N, 3) f32
  const float* cell = (const float*)d_in[2];    // (3, 3) f32
  int P = out_size / 5;

  cl5_fill<<<512, 256, 0, stream>>>((int*)d_out, out_size);
  cl5_wrap<<<CL5_NATOMS / 256, 256, 0, stream>>>(coords, cell);
  cl5_count<<<CL5_NGROUPS / 8, 512, 0, stream>>>(cell);
  cl5_scan<<<1, 1024, 0, stream>>>();
  cl5_emit<<<CL5_NGROUPS / 8, 512, 0, stream>>>(cell, (int*)d_out, P);
}

// Round 6
// 128.323 us; speedup vs baseline: 5.7177x; 5.7177x over previous
//
#include <hip/hip_runtime.h>

#define CL6_NATOMS 8192
#define CL6_NSHIFT 14
#define CL6_NROWS (CL6_NSHIFT * CL6_NATOMS)  // 114688 rows = (k, i)
#define CL6_NCHUNK 128                       // 8192 / 64 j-chunks per row
#define CL6_NTILE 112                        // scan tiles of 1024 rows
#define CL6_C2 ((float)(5.2 * 5.2))          // f32 compare, matches JAX weak promotion

__device__ const int cl6_shifts[CL6_NSHIFT][3] = {
    {0, 0, 0},
    {-1, 0, 0}, {-1, -1, 0}, {0, -1, 0}, {1, -1, 0},
    {-1, 1, -1}, {0, 1, -1}, {1, 1, -1}, {-1, 0, -1},
    {0, 0, -1}, {1, 0, -1}, {-1, -1, -1}, {0, -1, -1}, {1, -1, -1}};

// Module-owned scratch (d_ws unused). All consumed data rewritten every call.
__device__ float4 cl6_pp[CL6_NATOMS];                                  // wrapped coords
__device__ unsigned long long cl6_mask[(size_t)CL6_NROWS * CL6_NCHUNK]; // hit bitmasks
__device__ unsigned cl6_cnt[CL6_NROWS];
__device__ unsigned cl6_off[CL6_NROWS];
__device__ unsigned cl6_tot[CL6_NTILE];
__device__ unsigned cl6_tote[CL6_NTILE];

__device__ __forceinline__ void cl6_diag(const float* __restrict__ cell, float& dgx,
                                         float& dgy, float& dgz) {
  dgx = (float)sqrt((double)cell[0] * cell[0] + (double)cell[3] * cell[3] +
                    (double)cell[6] * cell[6]);
  dgy = (float)sqrt((double)cell[1] * cell[1] + (double)cell[4] * cell[4] +
                    (double)cell[7] * cell[7]);
  dgz = (float)sqrt((double)cell[2] * cell[2] + (double)cell[5] * cell[5] +
                    (double)cell[8] * cell[8]);
}

// frac = coords @ inv(cell); frac -= floor(frac); w = frac @ cell (f32 per-op RN)
__global__ __launch_bounds__(256) void cl6_wrap(const float* __restrict__ coords,
                                                const float* __restrict__ cell) {
  int i = blockIdx.x * blockDim.x + threadIdx.x;
  if (i >= CL6_NATOMS) return;
  double a00 = cell[0], a01 = cell[1], a02 = cell[2];
  double a10 = cell[3], a11 = cell[4], a12 = cell[5];
  double a20 = cell[6], a21 = cell[7], a22 = cell[8];
  double det = a00 * (a11 * a22 - a12 * a21) - a01 * (a10 * a22 - a12 * a20) +
               a02 * (a10 * a21 - a11 * a20);
  double id = 1.0 / det;
  float inv[3][3];
  inv[0][0] = (float)((a11 * a22 - a12 * a21) * id);
  inv[0][1] = (float)(-(a01 * a22 - a02 * a21) * id);
  inv[0][2] = (float)((a01 * a12 - a02 * a11) * id);
  inv[1][0] = (float)(-(a10 * a22 - a12 * a20) * id);
  inv[1][1] = (float)((a00 * a22 - a02 * a20) * id);
  inv[1][2] = (float)(-(a00 * a12 - a02 * a10) * id);
  inv[2][0] = (float)((a10 * a21 - a11 * a20) * id);
  inv[2][1] = (float)(-(a00 * a21 - a01 * a20) * id);
  inv[2][2] = (float)((a00 * a11 - a01 * a10) * id);

  float x = coords[3 * i], y = coords[3 * i + 1], z = coords[3 * i + 2];
  float fr[3], w[3];
#pragma unroll
  for (int c = 0; c < 3; ++c) {
    float f = __fadd_rn(__fadd_rn(__fmul_rn(x, inv[0][c]), __fmul_rn(y, inv[1][c])),
                        __fmul_rn(z, inv[2][c]));
    fr[c] = __fsub_rn(f, floorf(f));
  }
#pragma unroll
  for (int c = 0; c < 3; ++c) {
    w[c] = __fadd_rn(
        __fadd_rn(__fmul_rn(fr[0], cell[0 * 3 + c]), __fmul_rn(fr[1], cell[1 * 3 + c])),
        __fmul_rn(fr[2], cell[2 * 3 + c]));
  }
  cl6_pp[i] = make_float4(w[0], w[1], w[2], 0.0f);
}

// d2<=c2 forces shifted atom i into a cutoff-wide boundary slab (0.09 margin
// over f32 rounding slack). Pruned rows provably contribute zero pairs.
__device__ __forceinline__ bool cl6_alive(float xi, float yi, float zi, int sx, int sy,
                                          int sz, float dgx, float dgy, float dgz) {
  bool a = true;
  if (sx < 0) a = a && (xi >= dgx - 5.3f); else if (sx > 0) a = a && (xi <= 5.3f);
  if (sy < 0) a = a && (yi >= dgy - 5.3f); else if (sy > 0) a = a && (yi <= 5.3f);
  if (sz < 0) a = a && (zi >= dgz - 5.3f); else if (sz > 0) a = a && (zi <= 5.3f);
  return a;
}

// One wave per row: sweep j-chunks, store per-chunk hit mask + row count.
__global__ __launch_bounds__(512) void cl6_count(const float* __restrict__ cell) {
  int w = blockIdx.x * 8 + (threadIdx.x >> 6);
  int lane = threadIdx.x & 63;
  int k = w >> 13, i = w & (CL6_NATOMS - 1);

  float dgx, dgy, dgz;
  cl6_diag(cell, dgx, dgy, dgz);
  int sx = cl6_shifts[k][0], sy = cl6_shifts[k][1], sz = cl6_shifts[k][2];
  float sxf = __fmul_rn((float)sx, dgx);
  float syf = __fmul_rn((float)sy, dgy);
  float szf = __fmul_rn((float)sz, dgz);

  float4 pi = cl6_pp[i];
  if (k != 0 && !cl6_alive(pi.x, pi.y, pi.z, sx, sy, sz, dgx, dgy, dgz)) {
    if (lane == 0) cl6_cnt[w] = 0u;
    return;
  }
  int jc0 = (k == 0) ? (i >> 6) : 0;  // earlier chunks all fail i<j
  unsigned cnt = 0;
  for (int jc = jc0; jc < CL6_NCHUNK; ++jc) {
    int j = (jc << 6) + lane;
    float4 pj = cl6_pp[j];
    float dx = __fadd_rn(__fsub_rn(pi.x, pj.x), sxf);
    float dy = __fadd_rn(__fsub_rn(pi.y, pj.y), syf);
    float dz = __fadd_rn(__fsub_rn(pi.z, pj.z), szf);
    float d2 = __fadd_rn(__fadd_rn(__fmul_rn(dx, dx), __fmul_rn(dy, dy)),
                         __fmul_rn(dz, dz));
    bool ok = (d2 <= CL6_C2) && (k != 0 || i < j);
    unsigned long long m = __ballot(ok);
    if (lane == 0) cl6_mask[(size_t)w * CL6_NCHUNK + jc] = m;
    cnt += (unsigned)__popcll(m);
  }
  if (lane == 0) cl6_cnt[w] = cnt;
}

// Scan stage 1: per-tile (1024 rows) exclusive scan + tile total. 112 blocks.
__global__ __launch_bounds__(1024) void cl6_s1() {
  __shared__ unsigned sd[1024];
  int t = threadIdx.x;
  int gid = blockIdx.x * 1024 + t;
  unsigned v = cl6_cnt[gid];
  sd[t] = v;
  __syncthreads();
  unsigned acc = v;
  for (int off = 1; off < 1024; off <<= 1) {
    unsigned a = (t >= off) ? sd[t - off] : 0u;
    __syncthreads();
    acc += a;
    sd[t] = acc;
    __syncthreads();
  }
  cl6_off[gid] = acc - v;
  if (t == 1023) cl6_tot[blockIdx.x] = acc;
}

// Scan stage 2: exclusive scan of the 112 tile totals (single small block).
__global__ __launch_bounds__(128) void cl6_s2() {
  __shared__ unsigned sd[128];
  int t = threadIdx.x;
  unsigned v = (t < CL6_NTILE) ? cl6_tot[t] : 0u;
  sd[t] = v;
  __syncthreads();
  unsigned acc = v;
  for (int off = 1; off < 128; off <<= 1) {
    unsigned a = (t >= off) ? sd[t - off] : 0u;
    __syncthreads();
    acc += a;
    sd[t] = acc;
    __syncthreads();
  }
  if (t < CL6_NTILE) cl6_tote[t] = acc - v;
}

// Scan stage 3: add tile base to every row offset. 112 blocks.
__global__ __launch_bounds__(1024) void cl6_s3() {
  int gid = blockIdx.x * 1024 + threadIdx.x;
  cl6_off[gid] += cl6_tote[blockIdx.x];
}

__device__ __forceinline__ unsigned cl6_iscan(unsigned v, int lane) {
  for (int off = 1; off < 64; off <<= 1) {
    unsigned t = __shfl_up(v, off);
    if (lane >= off) v += t;
  }
  return v;
}

// One wave per row: expand stored masks into the int32 output stream
// [ i x P | j x P | (sx,sy,sz) x P ] — work proportional to pair count.
__global__ __launch_bounds__(512) void cl6_emit(const float* __restrict__ cell,
                                                int* __restrict__ out, int P) {
  int w = blockIdx.x * 8 + (threadIdx.x >> 6);
  int lane = threadIdx.x & 63;
  int k = w >> 13, i = w & (CL6_NATOMS - 1);

  float dgx, dgy, dgz;
  cl6_diag(cell, dgx, dgy, dgz);
  int sx = cl6_shifts[k][0], sy = cl6_shifts[k][1], sz = cl6_shifts[k][2];

  float4 pi = cl6_pp[i];
  if (k != 0 && !cl6_alive(pi.x, pi.y, pi.z, sx, sy, sz, dgx, dgy, dgz)) return;

  unsigned base = cl6_off[w];
  int jc0 = (k == 0) ? (i >> 6) : 0;
  size_t mb = (size_t)w * CL6_NCHUNK;
  unsigned long long m0 = (lane >= jc0) ? cl6_mask[mb + lane] : 0ull;
  unsigned long long m1 = (64 + lane >= jc0) ? cl6_mask[mb + 64 + lane] : 0ull;
  unsigned c0 = (unsigned)__popcll(m0), c1 = (unsigned)__popcll(m1);

  unsigned s0 = cl6_iscan(c0, lane);
  unsigned T0 = __shfl(s0, 63);
  unsigned e0 = s0 - c0;
  unsigned s1 = cl6_iscan(c1, lane);
  unsigned e1 = T0 + s1 - c1;

  unsigned p = base + e0;
  unsigned long long m = m0;
  while (m) {
    int b = __ffsll((long long)m) - 1;
    m &= m - 1;
    if (p < (unsigned)P) {
      int j = (lane << 6) + b;
      out[p] = i;
      out[P + p] = j;
      unsigned sp = 2u * (unsigned)P + 3u * p;
      out[sp] = sx;
      out[sp + 1] = sy;
      out[sp + 2] = sz;
    }
    ++p;
  }
  p = base + e1;
  m = m1;
  while (m) {
    int b = __ffsll((long long)m) - 1;
    m &= m - 1;
    if (p < (unsigned)P) {
      int j = ((64 + lane) << 6) + b;
      out[p] = i;
      out[P + p] = j;
      unsigned sp = 2u * (unsigned)P + 3u * p;
      out[sp] = sx;
      out[sp + 1] = sy;
      out[sp + 2] = sz;
    }
    ++p;
  }
}

extern "C" void kernel_launch(void* const* d_in, const int* in_sizes, int n_in,
                              void* d_out, int out_size, void* d_ws, size_t ws_size,
                              hipStream_t stream) {
  const float* coords = (const float*)d_in[1];  // (1, N, 3) f32
  const float* cell = (const float*)d_in[2];    // (3, 3) f32
  int P = out_size / 5;

  cl6_wrap<<<CL6_NATOMS / 256, 256, 0, stream>>>(coords, cell);
  cl6_count<<<CL6_NROWS / 8, 512, 0, stream>>>(cell);
  cl6_s1<<<CL6_NTILE, 1024, 0, stream>>>();
  cl6_s2<<<1, 128, 0, stream>>>();
  cl6_s3<<<CL6_NTILE, 1024, 0, stream>>>();
  cl6_emit<<<CL6_NROWS / 8, 512, 0, stream>>>(cell, (int*)d_out, P);
}